// Round 1
// baseline (1139.487 us; speedup 1.0000x reference)
//
#include <hip/hip_runtime.h>
#include <math.h>

#define N_NODES 10000
#define NPAD    10016
#define L_LEN   256
#define D_DIM   32
#define K_NBR   32
#define NTOT    (N_NODES * L_LEN)
#define EPS_BN  1e-5f

__device__ __forceinline__ float silu_f(float x) {
    return x / (1.0f + expf(-x));
}

// ---------- kernel 1: global sum & sumsq of pop ----------
__global__ void stats_kernel(const float* __restrict__ pop, float* __restrict__ stats) {
    __shared__ float s1[256], s2[256];
    int t = threadIdx.x;
    float a = 0.f, b = 0.f;
    for (int idx = blockIdx.x * 256 + t; idx < NTOT; idx += gridDim.x * 256) {
        float v = pop[idx];
        a += v; b += v * v;
    }
    s1[t] = a; s2[t] = b;
    __syncthreads();
    for (int s = 128; s > 0; s >>= 1) {
        if (t < s) { s1[t] += s1[t + s]; s2[t] += s2[t + s]; }
        __syncthreads();
    }
    if (t == 0) { atomicAdd(&stats[0], s1[0]); atomicAdd(&stats[1], s2[0]); }
}

// ---------- kernel 2: featurize: x[i,d] = mean_l silu(BN(conv(pop))) ----------
// BN folded: mean_d = w_d*M + b_d ; var_d = w_d^2 * Vc (global pop mean/var)
__global__ void feat_kernel(const float* __restrict__ pop,
                            const float* __restrict__ conv_w,
                            const float* __restrict__ conv_b,
                            const float* __restrict__ gamma,
                            const float* __restrict__ beta,
                            const float* __restrict__ stats,
                            float* __restrict__ X,
                            float* __restrict__ XT,
                            float* __restrict__ SQ) {
    __shared__ float row[L_LEN];
    __shared__ float part[256];
    int i = blockIdx.x;
    int t = threadIdx.x;
    row[t] = pop[i * L_LEN + t];
    __syncthreads();
    int d = t & 31, g = t >> 5;
    float M  = stats[0] * (1.0f / NTOT);
    float Vc = stats[1] * (1.0f / NTOT) - M * M;
    float w = conv_w[d], b = conv_b[d];
    float mean = fmaf(w, M, b);
    float var  = w * w * Vc;
    float sc = gamma[d] / sqrtf(var + EPS_BN);
    float bt = beta[d];
    float acc = 0.f;
    int l0 = g * 32;
    #pragma unroll
    for (int l = 0; l < 32; ++l) {
        float y = fmaf(row[l0 + l], w, b);
        float z = fmaf(y - mean, sc, bt);
        acc += silu_f(z);
    }
    part[t] = acc;
    __syncthreads();
    if (t < 32) {
        float s = 0.f;
        #pragma unroll
        for (int gg = 0; gg < 8; ++gg) s += part[gg * 32 + t];
        float xv = s * (1.0f / L_LEN);
        X[i * D_DIM + t] = xv;
        XT[t * N_NODES + i] = xv;
        part[t] = xv;
    }
    __syncthreads();
    if (t == 0) {
        float sq = 0.f;
        #pragma unroll
        for (int dd = 0; dd < 32; ++dd) sq += part[dd] * part[dd];
        SQ[i] = sq;
    }
}

// ---------- kernel 3: exact kNN via full-row LDS + radix-select ----------
// Matches jax.lax.top_k(-d2, k): set = all strictly-smaller + lowest-index ties.
__global__ __launch_bounds__(256) void knn_kernel(const float* __restrict__ X,
                                                  const float* __restrict__ XT,
                                                  const float* __restrict__ SQ,
                                                  int* __restrict__ NBR) {
    __shared__ unsigned int keys[NPAD];
    __shared__ float xi[D_DIM];
    __shared__ unsigned int hist[256];
    __shared__ unsigned int red[256];
    __shared__ unsigned int sprefix;
    __shared__ int swant, scnt, slast;
    int i = blockIdx.x;
    int t = threadIdx.x;
    if (t < D_DIM) xi[t] = X[i * D_DIM + t];
    if (t == 0) { sprefix = 0u; swant = K_NBR; scnt = 0; }
    __syncthreads();
    float sqi = SQ[i];
    // distance row -> order-preserving uint keys
    for (int j = t; j < NPAD; j += 256) {
        unsigned int kv = 0xFFFFFFFFu;
        if (j < N_NODES && j != i) {
            float acc = 0.f;
            #pragma unroll
            for (int d = 0; d < D_DIM; ++d)
                acc = fmaf(XT[d * N_NODES + j], xi[d], acc);
            float d2 = (sqi + SQ[j]) - 2.0f * acc;
            unsigned int u = __float_as_uint(d2);
            u ^= (u & 0x80000000u) ? 0xFFFFFFFFu : 0x80000000u;
            kv = u;
        }
        keys[j] = kv;
    }
    __syncthreads();
    // 4-round MSB radix select of the K-th smallest key
    for (int r = 0; r < 4; ++r) {
        hist[t] = 0u;
        __syncthreads();
        int shift = 24 - 8 * r;
        unsigned int pfx = sprefix;
        for (int j = t; j < NPAD; j += 256) {
            unsigned int u = keys[j];
            bool match = (r == 0) || ((u >> (shift + 8)) == pfx);
            if (match) atomicAdd(&hist[(u >> shift) & 255u], 1u);
        }
        __syncthreads();
        if (t == 0) {
            unsigned int cum = 0; int w = swant; unsigned int bkt = 0;
            for (; bkt < 256u; ++bkt) {
                if (cum + hist[bkt] >= (unsigned int)w) break;
                cum += hist[bkt];
            }
            swant = w - (int)cum;
            sprefix = (pfx << 8) | bkt;
        }
        __syncthreads();
    }
    unsigned int kth = sprefix;
    int wantEq = swant;          // how many ties at kth to take (lowest index first)
    // collect strictly-less (unordered; GCN sum is order-invariant)
    for (int j = t; j < N_NODES; j += 256) {
        if (keys[j] < kth) {
            int p = atomicAdd(&scnt, 1);
            NBR[i * K_NBR + p] = j;
        }
    }
    __syncthreads();
    int base = scnt;             // == K_NBR - wantEq
    int last = -1;
    for (int e = 0; e < wantEq; ++e) {
        unsigned int best = 0xFFFFFFFFu;
        for (int j = t; j < N_NODES; j += 256) {
            if (keys[j] == kth && j > last) best = min(best, (unsigned int)j);
        }
        red[t] = best;
        __syncthreads();
        for (int s = 128; s > 0; s >>= 1) {
            if (t < s) red[t] = min(red[t], red[t + s]);
            __syncthreads();
        }
        if (t == 0) {
            NBR[i * K_NBR + base + e] = (int)red[0];
            slast = (int)red[0];
        }
        __syncthreads();
        last = slast;
        __syncthreads();
    }
}

// ---------- kernel 4: H = X @ W (32x32) ----------
__global__ void gcn_mm(const float* __restrict__ X, const float* __restrict__ W,
                       float* __restrict__ H) {
    __shared__ float Ws[D_DIM * D_DIM];
    int t = threadIdx.x;
    #pragma unroll
    for (int q = 0; q < 4; ++q) Ws[q * 256 + t] = W[q * 256 + t];
    __syncthreads();
    int i = blockIdx.x * 8 + (t >> 5);
    int d = t & 31;
    const float* xr = X + i * D_DIM;
    float acc = 0.f;
    #pragma unroll
    for (int m = 0; m < D_DIM; ++m)
        acc = fmaf(xr[m], Ws[m * D_DIM + d], acc);
    H[i * D_DIM + d] = acc;
}

// ---------- kernel 5: agg = (H[i] + sum_nbr H[j]) * (1/33) + b ; optional SiLU ----------
__global__ void gcn_agg(const float* __restrict__ H, const int* __restrict__ NBR,
                        const float* __restrict__ bias, float* __restrict__ Xout,
                        int do_silu) {
    __shared__ int nb[256];
    int t = threadIdx.x;
    int i0 = blockIdx.x * 8;
    nb[t] = NBR[i0 * K_NBR + t];
    __syncthreads();
    int i = i0 + (t >> 5);
    int d = t & 31;
    float acc = H[i * D_DIM + d];
    int base = (t >> 5) * K_NBR;
    #pragma unroll 8
    for (int s = 0; s < K_NBR; ++s) {
        int j = nb[base + s];
        acc += H[j * D_DIM + d];
    }
    const float r = 1.0f / sqrtf(33.0f);   // deg == 33 for every node (k nbrs + self)
    const float nrm = r * r;
    float v = fmaf(acc, nrm, bias[d]);
    if (do_silu) v = silu_f(v);
    Xout[i * D_DIM + d] = v;
}

// ---------- kernel 6: HOUT = X @ out_w (32x3) ----------
__global__ void out_mm(const float* __restrict__ X, const float* __restrict__ W,
                       float* __restrict__ HOUT) {
    __shared__ float Ws[D_DIM * 3];
    int t = threadIdx.x;
    if (t < D_DIM * 3) Ws[t] = W[t];
    __syncthreads();
    int i = blockIdx.x * 256 + t;
    if (i >= N_NODES) return;
    float a0 = 0.f, a1 = 0.f, a2 = 0.f;
    #pragma unroll
    for (int m = 0; m < D_DIM; ++m) {
        float xv = X[i * D_DIM + m];
        a0 = fmaf(xv, Ws[m * 3 + 0], a0);
        a1 = fmaf(xv, Ws[m * 3 + 1], a1);
        a2 = fmaf(xv, Ws[m * 3 + 2], a2);
    }
    HOUT[i * 3 + 0] = a0; HOUT[i * 3 + 1] = a1; HOUT[i * 3 + 2] = a2;
}

// ---------- kernel 7: aggregate 3-dim + bias + softmax ----------
__global__ void final_kernel(const float* __restrict__ HOUT, const int* __restrict__ NBR,
                             const float* __restrict__ out_b, float* __restrict__ out) {
    int i = blockIdx.x * 256 + threadIdx.x;
    if (i >= N_NODES) return;
    float a0 = HOUT[i * 3 + 0], a1 = HOUT[i * 3 + 1], a2 = HOUT[i * 3 + 2];
    for (int s = 0; s < K_NBR; ++s) {
        int j = NBR[i * K_NBR + s];
        a0 += HOUT[j * 3 + 0];
        a1 += HOUT[j * 3 + 1];
        a2 += HOUT[j * 3 + 2];
    }
    const float r = 1.0f / sqrtf(33.0f);
    const float nrm = r * r;
    float v0 = fmaf(a0, nrm, out_b[0]);
    float v1 = fmaf(a1, nrm, out_b[1]);
    float v2 = fmaf(a2, nrm, out_b[2]);
    float m = fmaxf(v0, fmaxf(v1, v2));
    float e0 = expf(v0 - m), e1 = expf(v1 - m), e2 = expf(v2 - m);
    float inv = 1.0f / (e0 + e1 + e2);
    out[i * 3 + 0] = e0 * inv;
    out[i * 3 + 1] = e1 * inv;
    out[i * 3 + 2] = e2 * inv;
}

extern "C" void kernel_launch(void* const* d_in, const int* in_sizes, int n_in,
                              void* d_out, int out_size, void* d_ws, size_t ws_size,
                              hipStream_t stream) {
    const float* pop    = (const float*)d_in[0];
    const float* conv_w = (const float*)d_in[1];   // (D,1,1) -> flat D
    const float* conv_b = (const float*)d_in[2];
    const float* gamma  = (const float*)d_in[3];
    const float* beta   = (const float*)d_in[4];
    const float* gcn_ws = (const float*)d_in[5];   // (3,32,32)
    const float* gcn_bs = (const float*)d_in[6];   // (3,32)
    const float* out_w  = (const float*)d_in[7];   // (32,3)
    const float* out_b  = (const float*)d_in[8];   // (3,)
    // d_in[9] = k (always 32; hard-coded)

    char* ws = (char*)d_ws;
    // layout (bytes): stats[256] | X 1.28MB | XT 1.28MB | SQ 40192 | H 1.28MB | NBR 1.28MB | HOUT 120KB
    float* stats = (float*)ws;
    float* X     = (float*)(ws + 256);
    float* XT    = (float*)(ws + 256 + 1280000);
    float* SQ    = (float*)(ws + 256 + 2 * 1280000);
    float* H     = (float*)(ws + 256 + 2 * 1280000 + 40192);
    int*   NBR   = (int*)  (ws + 256 + 3 * 1280000 + 40192);
    float* HOUT  = (float*)(ws + 256 + 4 * 1280000 + 40192);
    float* out   = (float*)d_out;

    hipMemsetAsync(stats, 0, 2 * sizeof(float), stream);
    stats_kernel<<<512, 256, 0, stream>>>(pop, stats);
    feat_kernel<<<N_NODES, 256, 0, stream>>>(pop, conv_w, conv_b, gamma, beta, stats, X, XT, SQ);
    knn_kernel<<<N_NODES, 256, 0, stream>>>(X, XT, SQ, NBR);
    for (int l = 0; l < 3; ++l) {
        gcn_mm<<<N_NODES / 8, 256, 0, stream>>>(X, gcn_ws + l * D_DIM * D_DIM, H);
        gcn_agg<<<N_NODES / 8, 256, 0, stream>>>(H, NBR, gcn_bs + l * D_DIM, X, 1);
    }
    out_mm<<<(N_NODES + 255) / 256, 256, 0, stream>>>(X, out_w, HOUT);
    final_kernel<<<(N_NODES + 255) / 256, 256, 0, stream>>>(HOUT, NBR, out_b, out);
}

// Round 5
// 919.314 us; speedup vs baseline: 1.2395x; 1.2395x over previous
//
#include <hip/hip_runtime.h>
#include <math.h>

#define N_NODES 10000
#define NPAD    10016
#define NPAD2   10112          // candidate-padded row stride (mult of 128)
#define L_LEN   256
#define D_DIM   32
#define K_NBR   32
#define NTOT    (N_NODES * L_LEN)
#define EPS_BN  1e-5f
#define TQ      64
#define TC      128

typedef unsigned int uint4_ev __attribute__((ext_vector_type(4)));

__device__ __forceinline__ float silu_f(float x) {
    return x / (1.0f + expf(-x));
}

// ---------- kernel 1: global sum & sumsq of pop ----------
__global__ void stats_kernel(const float* __restrict__ pop, float* __restrict__ stats) {
    __shared__ float s1[256], s2[256];
    int t = threadIdx.x;
    float a = 0.f, b = 0.f;
    for (int idx = blockIdx.x * 256 + t; idx < NTOT; idx += gridDim.x * 256) {
        float v = pop[idx];
        a += v; b += v * v;
    }
    s1[t] = a; s2[t] = b;
    __syncthreads();
    for (int s = 128; s > 0; s >>= 1) {
        if (t < s) { s1[t] += s1[t + s]; s2[t] += s2[t + s]; }
        __syncthreads();
    }
    if (t == 0) { atomicAdd(&stats[0], s1[0]); atomicAdd(&stats[1], s2[0]); }
}

// ---------- kernel 2: featurize ----------
__global__ void feat_kernel(const float* __restrict__ pop,
                            const float* __restrict__ conv_w,
                            const float* __restrict__ conv_b,
                            const float* __restrict__ gamma,
                            const float* __restrict__ beta,
                            const float* __restrict__ stats,
                            float* __restrict__ X,
                            float* __restrict__ XT,
                            float* __restrict__ SQ) {
    __shared__ float row[L_LEN];
    __shared__ float part[256];
    int i = blockIdx.x;
    int t = threadIdx.x;
    row[t] = pop[i * L_LEN + t];
    __syncthreads();
    int d = t & 31, g = t >> 5;
    float M  = stats[0] * (1.0f / NTOT);
    float Vc = stats[1] * (1.0f / NTOT) - M * M;
    float w = conv_w[d], b = conv_b[d];
    float mean = fmaf(w, M, b);
    float var  = w * w * Vc;
    float sc = gamma[d] / sqrtf(var + EPS_BN);
    float bt = beta[d];
    float acc = 0.f;
    int l0 = g * 32;
    #pragma unroll
    for (int l = 0; l < 32; ++l) {
        float y = fmaf(row[l0 + l], w, b);
        float z = fmaf(y - mean, sc, bt);
        acc += silu_f(z);
    }
    part[t] = acc;
    __syncthreads();
    if (t < 32) {
        float s = 0.f;
        #pragma unroll
        for (int gg = 0; gg < 8; ++gg) s += part[gg * 32 + t];
        float xv = s * (1.0f / L_LEN);
        X[i * D_DIM + t] = xv;
        XT[t * N_NODES + i] = xv;
        part[t] = xv;
    }
    __syncthreads();
    if (t == 0) {
        float sq = 0.f;
        #pragma unroll
        for (int dd = 0; dd < 32; ++dd) sq += part[dd] * part[dd];
        SQ[i] = sq;
    }
}

// ---------- kernel 3a: tiled distance matrix -> order-preserving uint keys ----------
// block = 256 threads computes TQ x TC tile; thread micro-tile 4q x 8c.
__global__ __launch_bounds__(256) void dist_kernel(const float* __restrict__ X,
                                                   const float* __restrict__ SQ,
                                                   unsigned int* __restrict__ KEYS) {
    __shared__ float XQ[D_DIM][TQ];    // 8 KB, d-major
    __shared__ float XC[D_DIM][TC];    // 16 KB, d-major
    __shared__ float SQq[TQ], SQc[TC];
    int t = threadIdx.x;
    int c0 = blockIdx.x * TC;
    int q0 = blockIdx.y * TQ;

    // stage XQ (64x32 floats): thread t loads q=t/4, d0=(t%4)*8 (8 floats)
    {
        int q = t >> 2, d0 = (t & 3) * 8;
        float4 v0 = make_float4(0.f, 0.f, 0.f, 0.f), v1 = v0;
        if (q0 + q < N_NODES) {
            const float* p = X + (q0 + q) * D_DIM + d0;
            v0 = *(const float4*)p;
            v1 = *(const float4*)(p + 4);
        }
        XQ[d0 + 0][q] = v0.x; XQ[d0 + 1][q] = v0.y; XQ[d0 + 2][q] = v0.z; XQ[d0 + 3][q] = v0.w;
        XQ[d0 + 4][q] = v1.x; XQ[d0 + 5][q] = v1.y; XQ[d0 + 6][q] = v1.z; XQ[d0 + 7][q] = v1.w;
    }
    // stage XC (128x32 floats): thread t loads c=t/2, d0=(t%2)*16 (16 floats)
    {
        int c = t >> 1, d0 = (t & 1) * 16;
        float4 v[4];
        #pragma unroll
        for (int u = 0; u < 4; ++u) v[u] = make_float4(0.f, 0.f, 0.f, 0.f);
        if (c0 + c < N_NODES) {
            const float* p = X + (c0 + c) * D_DIM + d0;
            #pragma unroll
            for (int u = 0; u < 4; ++u) v[u] = *(const float4*)(p + 4 * u);
        }
        #pragma unroll
        for (int u = 0; u < 4; ++u) {
            XC[d0 + 4 * u + 0][c] = v[u].x; XC[d0 + 4 * u + 1][c] = v[u].y;
            XC[d0 + 4 * u + 2][c] = v[u].z; XC[d0 + 4 * u + 3][c] = v[u].w;
        }
    }
    if (t < TQ)  SQq[t] = (q0 + t < N_NODES) ? SQ[q0 + t] : 0.f;
    if (t < TC)  SQc[t] = (c0 + t < N_NODES) ? SQ[c0 + t] : 0.f;
    __syncthreads();

    int tr = t >> 4, tc = t & 15;
    int q = tr * 4, c = tc * 8;
    float acc[4][8];
    #pragma unroll
    for (int a = 0; a < 4; ++a)
        #pragma unroll
        for (int b = 0; b < 8; ++b) acc[a][b] = 0.f;

    #pragma unroll 4
    for (int d = 0; d < D_DIM; ++d) {
        float4 a  = *(const float4*)&XQ[d][q];
        float4 b0 = *(const float4*)&XC[d][c];
        float4 b1 = *(const float4*)&XC[d][c + 4];
        float av[4] = {a.x, a.y, a.z, a.w};
        float bv[8] = {b0.x, b0.y, b0.z, b0.w, b1.x, b1.y, b1.z, b1.w};
        #pragma unroll
        for (int aa = 0; aa < 4; ++aa)
            #pragma unroll
            for (int bb = 0; bb < 8; ++bb)
                acc[aa][bb] = fmaf(av[aa], bv[bb], acc[aa][bb]);
    }

    #pragma unroll
    for (int qq = 0; qq < 4; ++qq) {
        int gq = q0 + q + qq;
        if (gq >= N_NODES) continue;
        float sqq = SQq[q + qq];
        unsigned int kk[8];
        #pragma unroll
        for (int cc = 0; cc < 8; ++cc) {
            int gc = c0 + c + cc;
            float d2 = (sqq + SQc[c + cc]) - 2.0f * acc[qq][cc];
            unsigned int u = __float_as_uint(d2);
            u ^= (u & 0x80000000u) ? 0xFFFFFFFFu : 0x80000000u;
            if (gc >= N_NODES || gc == gq) u = 0xFFFFFFFFu;
            kk[cc] = u;
        }
        unsigned int* dst = KEYS + (size_t)gq * NPAD2 + (c0 + c);
        uint4_ev w0 = { kk[0], kk[1], kk[2], kk[3] };
        uint4_ev w1 = { kk[4], kk[5], kk[6], kk[7] };
        __builtin_nontemporal_store(w0, (uint4_ev*)dst);
        __builtin_nontemporal_store(w1, (uint4_ev*)(dst + 4));
    }
}

// ---------- kernel 3b: per-row exact top-k radix select (parallel bucket scan) ----------
__global__ __launch_bounds__(256) void select_kernel(const unsigned int* __restrict__ KEYS,
                                                     int* __restrict__ NBR) {
    __shared__ __align__(16) unsigned int keys[NPAD2];
    __shared__ unsigned int hist[256];
    __shared__ unsigned int scan[256];
    __shared__ unsigned int red[256];
    __shared__ unsigned int sprefix;
    __shared__ int swant, scnt, slast;
    int i = blockIdx.x;
    int t = threadIdx.x;
    if (t == 0) { sprefix = 0u; swant = K_NBR; scnt = 0; }
    const unsigned int* rowp = KEYS + (size_t)i * NPAD2;
    for (int jj = 4 * t; jj < NPAD2; jj += 1024) {
        uint4_ev v = __builtin_nontemporal_load((const uint4_ev*)(rowp + jj));
        *(uint4_ev*)&keys[jj] = v;
    }
    __syncthreads();

    for (int r = 0; r < 4; ++r) {
        hist[t] = 0u;
        __syncthreads();
        int shift = 24 - 8 * r;
        unsigned int pfx = sprefix;
        int want = swant;
        for (int j = t; j < NPAD2; j += 256) {
            unsigned int u = keys[j];
            bool match = (r == 0) || ((u >> (shift + 8)) == pfx);
            if (match) atomicAdd(&hist[(u >> shift) & 255u], 1u);
        }
        __syncthreads();
        unsigned int cnt = hist[t];
        scan[t] = cnt;
        __syncthreads();
        for (int off = 1; off < 256; off <<= 1) {
            unsigned int v = (t >= off) ? scan[t - off] : 0u;
            __syncthreads();
            scan[t] += v;
            __syncthreads();
        }
        unsigned int incl = scan[t];
        unsigned int excl = incl - cnt;
        if (excl < (unsigned int)want && (unsigned int)want <= incl) {
            swant = want - (int)excl;
            sprefix = (pfx << 8) | (unsigned int)t;
        }
        __syncthreads();
    }

    unsigned int kth = sprefix;
    int wantEq = swant;
    for (int j = t; j < N_NODES; j += 256) {
        if (keys[j] < kth) {
            int p = atomicAdd(&scnt, 1);
            NBR[i * K_NBR + p] = j;
        }
    }
    __syncthreads();
    int base = scnt;
    int last = -1;
    for (int e = 0; e < wantEq; ++e) {
        unsigned int best = 0xFFFFFFFFu;
        for (int j = t; j < N_NODES; j += 256) {
            if (keys[j] == kth && j > last) best = min(best, (unsigned int)j);
        }
        red[t] = best;
        __syncthreads();
        for (int s = 128; s > 0; s >>= 1) {
            if (t < s) red[t] = min(red[t], red[t + s]);
            __syncthreads();
        }
        if (t == 0) {
            NBR[i * K_NBR + base + e] = (int)red[0];
            slast = (int)red[0];
        }
        __syncthreads();
        last = slast;
        __syncthreads();
    }
}

// ---------- fallback kNN (used only if ws_size too small for KEYS) ----------
__global__ __launch_bounds__(256) void knn_kernel(const float* __restrict__ X,
                                                  const float* __restrict__ XT,
                                                  const float* __restrict__ SQ,
                                                  int* __restrict__ NBR) {
    __shared__ unsigned int keys[NPAD];
    __shared__ float xi[D_DIM];
    __shared__ unsigned int hist[256];
    __shared__ unsigned int scan[256];
    __shared__ unsigned int sprefix;
    __shared__ int swant, scnt, slast;
    int i = blockIdx.x;
    int t = threadIdx.x;
    if (t < D_DIM) xi[t] = X[i * D_DIM + t];
    if (t == 0) { sprefix = 0u; swant = K_NBR; scnt = 0; }
    __syncthreads();
    float sqi = SQ[i];
    for (int j = t; j < NPAD; j += 256) {
        unsigned int kv = 0xFFFFFFFFu;
        if (j < N_NODES && j != i) {
            float acc = 0.f;
            #pragma unroll
            for (int d = 0; d < D_DIM; ++d)
                acc = fmaf(XT[d * N_NODES + j], xi[d], acc);
            float d2 = (sqi + SQ[j]) - 2.0f * acc;
            unsigned int u = __float_as_uint(d2);
            u ^= (u & 0x80000000u) ? 0xFFFFFFFFu : 0x80000000u;
            kv = u;
        }
        keys[j] = kv;
    }
    __syncthreads();
    for (int r = 0; r < 4; ++r) {
        hist[t] = 0u;
        __syncthreads();
        int shift = 24 - 8 * r;
        unsigned int pfx = sprefix;
        int want = swant;
        for (int j = t; j < NPAD; j += 256) {
            unsigned int u = keys[j];
            bool match = (r == 0) || ((u >> (shift + 8)) == pfx);
            if (match) atomicAdd(&hist[(u >> shift) & 255u], 1u);
        }
        __syncthreads();
        unsigned int cnt = hist[t];
        scan[t] = cnt;
        __syncthreads();
        for (int off = 1; off < 256; off <<= 1) {
            unsigned int v = (t >= off) ? scan[t - off] : 0u;
            __syncthreads();
            scan[t] += v;
            __syncthreads();
        }
        unsigned int incl = scan[t];
        unsigned int excl = incl - cnt;
        if (excl < (unsigned int)want && (unsigned int)want <= incl) {
            swant = want - (int)excl;
            sprefix = (pfx << 8) | (unsigned int)t;
        }
        __syncthreads();
    }
    unsigned int kth = sprefix;
    int wantEq = swant;
    for (int j = t; j < N_NODES; j += 256) {
        if (keys[j] < kth) {
            int p = atomicAdd(&scnt, 1);
            NBR[i * K_NBR + p] = j;
        }
    }
    __syncthreads();
    int base = scnt;
    int last = -1;
    for (int e = 0; e < wantEq; ++e) {
        unsigned int best = 0xFFFFFFFFu;
        for (int j = t; j < N_NODES; j += 256) {
            if (keys[j] == kth && j > last) best = min(best, (unsigned int)j);
        }
        scan[t] = best;
        __syncthreads();
        for (int s = 128; s > 0; s >>= 1) {
            if (t < s) scan[t] = min(scan[t], scan[t + s]);
            __syncthreads();
        }
        if (t == 0) {
            NBR[i * K_NBR + base + e] = (int)scan[0];
            slast = (int)scan[0];
        }
        __syncthreads();
        last = slast;
        __syncthreads();
    }
}

// ---------- kernel 4: H = X @ W (32x32) ----------
__global__ void gcn_mm(const float* __restrict__ X, const float* __restrict__ W,
                       float* __restrict__ H) {
    __shared__ float Ws[D_DIM * D_DIM];
    int t = threadIdx.x;
    #pragma unroll
    for (int q = 0; q < 4; ++q) Ws[q * 256 + t] = W[q * 256 + t];
    __syncthreads();
    int i = blockIdx.x * 8 + (t >> 5);
    int d = t & 31;
    const float* xr = X + i * D_DIM;
    float acc = 0.f;
    #pragma unroll
    for (int m = 0; m < D_DIM; ++m)
        acc = fmaf(xr[m], Ws[m * D_DIM + d], acc);
    H[i * D_DIM + d] = acc;
}

// ---------- kernel 5: aggregate + bias (+SiLU) ----------
__global__ void gcn_agg(const float* __restrict__ H, const int* __restrict__ NBR,
                        const float* __restrict__ bias, float* __restrict__ Xout,
                        int do_silu) {
    __shared__ int nb[256];
    int t = threadIdx.x;
    int i0 = blockIdx.x * 8;
    nb[t] = NBR[i0 * K_NBR + t];
    __syncthreads();
    int i = i0 + (t >> 5);
    int d = t & 31;
    float acc = H[i * D_DIM + d];
    int base = (t >> 5) * K_NBR;
    #pragma unroll 8
    for (int s = 0; s < K_NBR; ++s) {
        int j = nb[base + s];
        acc += H[j * D_DIM + d];
    }
    const float r = 1.0f / sqrtf(33.0f);   // deg == 33 for every node
    const float nrm = r * r;
    float v = fmaf(acc, nrm, bias[d]);
    if (do_silu) v = silu_f(v);
    Xout[i * D_DIM + d] = v;
}

// ---------- kernel 6: HOUT = X @ out_w (32x3) ----------
__global__ void out_mm(const float* __restrict__ X, const float* __restrict__ W,
                       float* __restrict__ HOUT) {
    __shared__ float Ws[D_DIM * 3];
    int t = threadIdx.x;
    if (t < D_DIM * 3) Ws[t] = W[t];
    __syncthreads();
    int i = blockIdx.x * 256 + t;
    if (i >= N_NODES) return;
    float a0 = 0.f, a1 = 0.f, a2 = 0.f;
    #pragma unroll
    for (int m = 0; m < D_DIM; ++m) {
        float xv = X[i * D_DIM + m];
        a0 = fmaf(xv, Ws[m * 3 + 0], a0);
        a1 = fmaf(xv, Ws[m * 3 + 1], a1);
        a2 = fmaf(xv, Ws[m * 3 + 2], a2);
    }
    HOUT[i * 3 + 0] = a0; HOUT[i * 3 + 1] = a1; HOUT[i * 3 + 2] = a2;
}

// ---------- kernel 7: aggregate 3-dim + bias + softmax ----------
__global__ void final_kernel(const float* __restrict__ HOUT, const int* __restrict__ NBR,
                             const float* __restrict__ out_b, float* __restrict__ out) {
    int i = blockIdx.x * 256 + threadIdx.x;
    if (i >= N_NODES) return;
    float a0 = HOUT[i * 3 + 0], a1 = HOUT[i * 3 + 1], a2 = HOUT[i * 3 + 2];
    for (int s = 0; s < K_NBR; ++s) {
        int j = NBR[i * K_NBR + s];
        a0 += HOUT[j * 3 + 0];
        a1 += HOUT[j * 3 + 1];
        a2 += HOUT[j * 3 + 2];
    }
    const float r = 1.0f / sqrtf(33.0f);
    const float nrm = r * r;
    float v0 = fmaf(a0, nrm, out_b[0]);
    float v1 = fmaf(a1, nrm, out_b[1]);
    float v2 = fmaf(a2, nrm, out_b[2]);
    float m = fmaxf(v0, fmaxf(v1, v2));
    float e0 = expf(v0 - m), e1 = expf(v1 - m), e2 = expf(v2 - m);
    float inv = 1.0f / (e0 + e1 + e2);
    out[i * 3 + 0] = e0 * inv;
    out[i * 3 + 1] = e1 * inv;
    out[i * 3 + 2] = e2 * inv;
}

extern "C" void kernel_launch(void* const* d_in, const int* in_sizes, int n_in,
                              void* d_out, int out_size, void* d_ws, size_t ws_size,
                              hipStream_t stream) {
    const float* pop    = (const float*)d_in[0];
    const float* conv_w = (const float*)d_in[1];
    const float* conv_b = (const float*)d_in[2];
    const float* gamma  = (const float*)d_in[3];
    const float* beta   = (const float*)d_in[4];
    const float* gcn_ws = (const float*)d_in[5];
    const float* gcn_bs = (const float*)d_in[6];
    const float* out_w  = (const float*)d_in[7];
    const float* out_b  = (const float*)d_in[8];

    char* ws = (char*)d_ws;
    // offsets (bytes)
    const size_t o_stats = 0;
    const size_t o_X     = 256;
    const size_t o_XT    = o_X + 1280000;
    const size_t o_SQ    = o_XT + 1280000;
    const size_t o_H     = o_SQ + 40192;
    const size_t o_NBR   = o_H + 1280000;
    const size_t o_HOUT  = o_NBR + 1280000;
    const size_t o_KEYS  = o_HOUT + 120064;
    const size_t need    = o_KEYS + (size_t)N_NODES * NPAD2 * 4;   // ~409.8 MB

    float* stats = (float*)(ws + o_stats);
    float* X     = (float*)(ws + o_X);
    float* XT    = (float*)(ws + o_XT);
    float* SQ    = (float*)(ws + o_SQ);
    float* H     = (float*)(ws + o_H);
    int*   NBR   = (int*)  (ws + o_NBR);
    float* HOUT  = (float*)(ws + o_HOUT);
    unsigned int* KEYS = (unsigned int*)(ws + o_KEYS);
    float* out   = (float*)d_out;

    (void)hipMemsetAsync(stats, 0, 2 * sizeof(float), stream);
    stats_kernel<<<512, 256, 0, stream>>>(pop, stats);
    feat_kernel<<<N_NODES, 256, 0, stream>>>(pop, conv_w, conv_b, gamma, beta, stats, X, XT, SQ);

    if (ws_size >= need) {
        dim3 grid((N_NODES + TC - 1) / TC, (N_NODES + TQ - 1) / TQ);  // (79, 157)
        dist_kernel<<<grid, 256, 0, stream>>>(X, SQ, KEYS);
        select_kernel<<<N_NODES, 256, 0, stream>>>(KEYS, NBR);
    } else {
        knn_kernel<<<N_NODES, 256, 0, stream>>>(X, XT, SQ, NBR);
    }

    for (int l = 0; l < 3; ++l) {
        gcn_mm<<<N_NODES / 8, 256, 0, stream>>>(X, gcn_ws + l * D_DIM * D_DIM, H);
        gcn_agg<<<N_NODES / 8, 256, 0, stream>>>(H, NBR, gcn_bs + l * D_DIM, X, 1);
    }
    out_mm<<<(N_NODES + 255) / 256, 256, 0, stream>>>(X, out_w, HOUT);
    final_kernel<<<(N_NODES + 255) / 256, 256, 0, stream>>>(HOUT, NBR, out_b, out);
}

// Round 6
// 766.519 us; speedup vs baseline: 1.4866x; 1.1993x over previous
//
#include <hip/hip_runtime.h>
#include <math.h>

#define N_NODES 10000
#define NPAD    10016          // mult of 4; padded key-row length
#define L_LEN   256
#define D_DIM   32
#define K_NBR   32
#define NTOT    (N_NODES * L_LEN)
#define EPS_BN  1e-5f
#define QB      3              // queries per block in knn3
#define BT      1024           // threads per block in knn3
#define SD      3              // float4 stripes: 3*1024*4 = 12288 >= NPAD

typedef unsigned int uint4_ev __attribute__((ext_vector_type(4)));

__device__ __forceinline__ float silu_f(float x) {
    return x / (1.0f + expf(-x));
}

// ---------- kernel 1: global sum & sumsq of pop ----------
__global__ void stats_kernel(const float* __restrict__ pop, float* __restrict__ stats) {
    __shared__ float s1[256], s2[256];
    int t = threadIdx.x;
    float a = 0.f, b = 0.f;
    for (int idx = blockIdx.x * 256 + t; idx < NTOT; idx += gridDim.x * 256) {
        float v = pop[idx];
        a += v; b += v * v;
    }
    s1[t] = a; s2[t] = b;
    __syncthreads();
    for (int s = 128; s > 0; s >>= 1) {
        if (t < s) { s1[t] += s1[t + s]; s2[t] += s2[t + s]; }
        __syncthreads();
    }
    if (t == 0) { atomicAdd(&stats[0], s1[0]); atomicAdd(&stats[1], s2[0]); }
}

// ---------- kernel 2: featurize (BN folded to global scalar stats) ----------
__global__ void feat_kernel(const float* __restrict__ pop,
                            const float* __restrict__ conv_w,
                            const float* __restrict__ conv_b,
                            const float* __restrict__ gamma,
                            const float* __restrict__ beta,
                            const float* __restrict__ stats,
                            float* __restrict__ X,
                            float* __restrict__ XT,
                            float* __restrict__ SQ) {
    __shared__ float row[L_LEN];
    __shared__ float part[256];
    int i = blockIdx.x;
    int t = threadIdx.x;
    row[t] = pop[i * L_LEN + t];
    __syncthreads();
    int d = t & 31, g = t >> 5;
    float M  = stats[0] * (1.0f / NTOT);
    float Vc = stats[1] * (1.0f / NTOT) - M * M;
    float w = conv_w[d], b = conv_b[d];
    float mean = fmaf(w, M, b);
    float var  = w * w * Vc;
    float sc = gamma[d] / sqrtf(var + EPS_BN);
    float bt = beta[d];
    float acc = 0.f;
    int l0 = g * 32;
    #pragma unroll
    for (int l = 0; l < 32; ++l) {
        float y = fmaf(row[l0 + l], w, b);
        float z = fmaf(y - mean, sc, bt);
        acc += silu_f(z);
    }
    part[t] = acc;
    __syncthreads();
    if (t < 32) {
        float s = 0.f;
        #pragma unroll
        for (int gg = 0; gg < 8; ++gg) s += part[gg * 32 + t];
        float xv = s * (1.0f / L_LEN);
        X[i * D_DIM + t] = xv;
        XT[t * N_NODES + i] = xv;
        part[t] = xv;
    }
    __syncthreads();
    if (t == 0) {
        float sq = 0.f;
        #pragma unroll
        for (int dd = 0; dd < 32; ++dd) sq += part[dd] * part[dd];
        SQ[i] = sq;
    }
}

// ---------- kernel 3: fused multi-query kNN ----------
// QB=3 queries/block share each XT read (3x less L2 traffic than 1-query blocks).
// Keys (3 x NPAD u32 = 120 KB) live in dynamic LDS; exact 4-round radix select
// with single-wave shfl exscan; ties broken by lowest index (top_k semantics).
__global__ __launch_bounds__(BT) void knn3_kernel(const float* __restrict__ X,
                                                  const float* __restrict__ XT,
                                                  const float* __restrict__ SQ,
                                                  int* __restrict__ NBR) {
    extern __shared__ unsigned int keys[];      // [QB][NPAD]
    __shared__ float qv[QB][D_DIM];
    __shared__ float sqq[QB];
    __shared__ unsigned int hist[256];
    __shared__ unsigned int sprefix;
    __shared__ int swant, scnt, slast;

    int t = threadIdx.x;
    int q0 = blockIdx.x * QB;

    if (t < QB * D_DIM) {
        int q = t >> 5, d = t & 31;
        int gq = q0 + q;
        qv[q][d] = (gq < N_NODES) ? X[gq * D_DIM + d] : 0.f;
    }
    if (t < QB) sqq[t] = (q0 + t < N_NODES) ? SQ[q0 + t] : 0.f;
    __syncthreads();

    // ---- distance phase: d-outer, j-inner (float4), acc[q][stripe*4+jj] ----
    float acc[QB][SD * 4];
    #pragma unroll
    for (int q = 0; q < QB; ++q)
        #pragma unroll
        for (int s = 0; s < SD * 4; ++s) acc[q][s] = 0.f;

    #pragma unroll 2
    for (int d = 0; d < D_DIM; ++d) {
        float qd0 = qv[0][d], qd1 = qv[1][d], qd2 = qv[2][d];
        const float4* xr4 = (const float4*)(XT + d * N_NODES);
        #pragma unroll
        for (int s = 0; s < SD; ++s) {
            int i4 = t + s * BT;                 // float4 index; j = 4*i4..4*i4+3
            float4 xv = make_float4(0.f, 0.f, 0.f, 0.f);
            if (i4 < N_NODES / 4) xv = xr4[i4];
            acc[0][s * 4 + 0] = fmaf(qd0, xv.x, acc[0][s * 4 + 0]);
            acc[0][s * 4 + 1] = fmaf(qd0, xv.y, acc[0][s * 4 + 1]);
            acc[0][s * 4 + 2] = fmaf(qd0, xv.z, acc[0][s * 4 + 2]);
            acc[0][s * 4 + 3] = fmaf(qd0, xv.w, acc[0][s * 4 + 3]);
            acc[1][s * 4 + 0] = fmaf(qd1, xv.x, acc[1][s * 4 + 0]);
            acc[1][s * 4 + 1] = fmaf(qd1, xv.y, acc[1][s * 4 + 1]);
            acc[1][s * 4 + 2] = fmaf(qd1, xv.z, acc[1][s * 4 + 2]);
            acc[1][s * 4 + 3] = fmaf(qd1, xv.w, acc[1][s * 4 + 3]);
            acc[2][s * 4 + 0] = fmaf(qd2, xv.x, acc[2][s * 4 + 0]);
            acc[2][s * 4 + 1] = fmaf(qd2, xv.y, acc[2][s * 4 + 1]);
            acc[2][s * 4 + 2] = fmaf(qd2, xv.z, acc[2][s * 4 + 2]);
            acc[2][s * 4 + 3] = fmaf(qd2, xv.w, acc[2][s * 4 + 3]);
        }
    }

    // ---- key phase: d2 -> order-preserving u32, write to LDS ----
    const float4* sq4p = (const float4*)SQ;
    #pragma unroll
    for (int s = 0; s < SD; ++s) {
        int i4 = t + s * BT;
        int j4 = 4 * i4;
        if (j4 < NPAD) {
            float4 sj = make_float4(0.f, 0.f, 0.f, 0.f);
            if (i4 < N_NODES / 4) sj = sq4p[i4];
            float sjv[4] = { sj.x, sj.y, sj.z, sj.w };
            #pragma unroll
            for (int q = 0; q < QB; ++q) {
                int gq = q0 + q;
                unsigned int kk[4];
                #pragma unroll
                for (int jj = 0; jj < 4; ++jj) {
                    int j = j4 + jj;
                    unsigned int kv = 0xFFFFFFFFu;
                    if (j < N_NODES && gq < N_NODES && j != gq) {
                        float d2 = (sqq[q] + sjv[jj]) - 2.0f * acc[q][s * 4 + jj];
                        unsigned int u = __float_as_uint(d2);
                        u ^= (u & 0x80000000u) ? 0xFFFFFFFFu : 0x80000000u;
                        kv = u;
                    }
                    kk[jj] = kv;
                }
                uint4_ev w = { kk[0], kk[1], kk[2], kk[3] };
                *(uint4_ev*)&keys[q * NPAD + j4] = w;
            }
        }
    }
    __syncthreads();

    // ---- per-query exact radix select ----
    for (int q = 0; q < QB; ++q) {
        int gq = q0 + q;
        if (gq >= N_NODES) break;               // block-uniform
        unsigned int* kq = keys + q * NPAD;
        if (t == 0) { sprefix = 0u; swant = K_NBR; scnt = 0; }
        __syncthreads();

        for (int r = 0; r < 4; ++r) {
            if (t < 256) hist[t] = 0u;
            __syncthreads();
            unsigned int pfxR = sprefix;
            int wantR = swant;
            int shift = 24 - 8 * r;
            for (int s = 0; s < 10; ++s) {
                int j = t + s * BT;
                if (j < NPAD) {
                    unsigned int u = kq[j];
                    bool match = (r == 0) || ((u >> (shift + 8)) == pfxR);
                    if (match) atomicAdd(&hist[(u >> shift) & 255u], 1u);
                }
            }
            __syncthreads();
            if (t < 64) {
                int lane = t;
                unsigned int c[4];
                unsigned int gsum = 0u;
                #pragma unroll
                for (int i = 0; i < 4; ++i) { c[i] = hist[4 * lane + i]; gsum += c[i]; }
                unsigned int x = gsum;
                #pragma unroll
                for (int off = 1; off < 64; off <<= 1) {
                    unsigned int y = (unsigned int)__shfl_up((int)x, off);
                    if (lane >= off) x += y;
                }
                unsigned int e = x - gsum;      // exclusive prefix of this 4-bucket group
                #pragma unroll
                for (int i = 0; i < 4; ++i) {
                    if (e < (unsigned int)wantR && (unsigned int)wantR <= e + c[i]) {
                        swant = wantR - (int)e;
                        sprefix = (pfxR << 8) | (unsigned int)(4 * lane + i);
                    }
                    e += c[i];
                }
            }
            __syncthreads();
        }

        unsigned int kth = sprefix;
        int wantEq = swant;
        // strictly-less (unordered; downstream sum is order-invariant)
        for (int s = 0; s < 10; ++s) {
            int j = t + s * BT;
            if (j < N_NODES && kq[j] < kth) {
                int p = atomicAdd(&scnt, 1);
                NBR[gq * K_NBR + p] = j;
            }
        }
        __syncthreads();
        int base = scnt;                         // == K_NBR - wantEq
        int last = -1;
        for (int e = 0; e < wantEq; ++e) {
            unsigned int best = 0xFFFFFFFFu;
            for (int s = 0; s < 10; ++s) {
                int j = t + s * BT;
                if (j < N_NODES && kq[j] == kth && j > last)
                    best = best < (unsigned int)j ? best : (unsigned int)j;
            }
            #pragma unroll
            for (int off = 32; off > 0; off >>= 1) {
                unsigned int o = (unsigned int)__shfl_xor((int)best, off);
                best = best < o ? best : o;
            }
            if ((t & 63) == 0) hist[t >> 6] = best;   // 16 wave leaders
            __syncthreads();
            if (t == 0) {
                unsigned int m = 0xFFFFFFFFu;
                #pragma unroll
                for (int w = 0; w < 16; ++w) m = m < hist[w] ? m : hist[w];
                NBR[gq * K_NBR + base + e] = (int)m;
                slast = (int)m;
            }
            __syncthreads();
            last = slast;
            __syncthreads();
        }
    }
}

// ---------- kernel 4: H = X @ W (32x32) ----------
__global__ void gcn_mm(const float* __restrict__ X, const float* __restrict__ W,
                       float* __restrict__ H) {
    __shared__ float Ws[D_DIM * D_DIM];
    int t = threadIdx.x;
    #pragma unroll
    for (int q = 0; q < 4; ++q) Ws[q * 256 + t] = W[q * 256 + t];
    __syncthreads();
    int i = blockIdx.x * 8 + (t >> 5);
    int d = t & 31;
    const float* xr = X + i * D_DIM;
    float acc = 0.f;
    #pragma unroll
    for (int m = 0; m < D_DIM; ++m)
        acc = fmaf(xr[m], Ws[m * D_DIM + d], acc);
    H[i * D_DIM + d] = acc;
}

// ---------- kernel 5: aggregate + bias (+SiLU) ----------
__global__ void gcn_agg(const float* __restrict__ H, const int* __restrict__ NBR,
                        const float* __restrict__ bias, float* __restrict__ Xout,
                        int do_silu) {
    __shared__ int nb[256];
    int t = threadIdx.x;
    int i0 = blockIdx.x * 8;
    nb[t] = NBR[i0 * K_NBR + t];
    __syncthreads();
    int i = i0 + (t >> 5);
    int d = t & 31;
    float acc = H[i * D_DIM + d];
    int base = (t >> 5) * K_NBR;
    #pragma unroll 8
    for (int s = 0; s < K_NBR; ++s) {
        int j = nb[base + s];
        acc += H[j * D_DIM + d];
    }
    const float r = 1.0f / sqrtf(33.0f);   // deg == 33 for every node
    const float nrm = r * r;
    float v = fmaf(acc, nrm, bias[d]);
    if (do_silu) v = silu_f(v);
    Xout[i * D_DIM + d] = v;
}

// ---------- kernel 6: HOUT = X @ out_w (32x3) ----------
__global__ void out_mm(const float* __restrict__ X, const float* __restrict__ W,
                       float* __restrict__ HOUT) {
    __shared__ float Ws[D_DIM * 3];
    int t = threadIdx.x;
    if (t < D_DIM * 3) Ws[t] = W[t];
    __syncthreads();
    int i = blockIdx.x * 256 + t;
    if (i >= N_NODES) return;
    float a0 = 0.f, a1 = 0.f, a2 = 0.f;
    #pragma unroll
    for (int m = 0; m < D_DIM; ++m) {
        float xv = X[i * D_DIM + m];
        a0 = fmaf(xv, Ws[m * 3 + 0], a0);
        a1 = fmaf(xv, Ws[m * 3 + 1], a1);
        a2 = fmaf(xv, Ws[m * 3 + 2], a2);
    }
    HOUT[i * 3 + 0] = a0; HOUT[i * 3 + 1] = a1; HOUT[i * 3 + 2] = a2;
}

// ---------- kernel 7: aggregate 3-dim + bias + softmax ----------
__global__ void final_kernel(const float* __restrict__ HOUT, const int* __restrict__ NBR,
                             const float* __restrict__ out_b, float* __restrict__ out) {
    int i = blockIdx.x * 256 + threadIdx.x;
    if (i >= N_NODES) return;
    float a0 = HOUT[i * 3 + 0], a1 = HOUT[i * 3 + 1], a2 = HOUT[i * 3 + 2];
    for (int s = 0; s < K_NBR; ++s) {
        int j = NBR[i * K_NBR + s];
        a0 += HOUT[j * 3 + 0];
        a1 += HOUT[j * 3 + 1];
        a2 += HOUT[j * 3 + 2];
    }
    const float r = 1.0f / sqrtf(33.0f);
    const float nrm = r * r;
    float v0 = fmaf(a0, nrm, out_b[0]);
    float v1 = fmaf(a1, nrm, out_b[1]);
    float v2 = fmaf(a2, nrm, out_b[2]);
    float m = fmaxf(v0, fmaxf(v1, v2));
    float e0 = expf(v0 - m), e1 = expf(v1 - m), e2 = expf(v2 - m);
    float inv = 1.0f / (e0 + e1 + e2);
    out[i * 3 + 0] = e0 * inv;
    out[i * 3 + 1] = e1 * inv;
    out[i * 3 + 2] = e2 * inv;
}

extern "C" void kernel_launch(void* const* d_in, const int* in_sizes, int n_in,
                              void* d_out, int out_size, void* d_ws, size_t ws_size,
                              hipStream_t stream) {
    const float* pop    = (const float*)d_in[0];
    const float* conv_w = (const float*)d_in[1];
    const float* conv_b = (const float*)d_in[2];
    const float* gamma  = (const float*)d_in[3];
    const float* beta   = (const float*)d_in[4];
    const float* gcn_ws = (const float*)d_in[5];
    const float* gcn_bs = (const float*)d_in[6];
    const float* out_w  = (const float*)d_in[7];
    const float* out_b  = (const float*)d_in[8];

    char* ws = (char*)d_ws;
    const size_t o_stats = 0;
    const size_t o_X     = 256;
    const size_t o_XT    = o_X + 1280000;
    const size_t o_SQ    = o_XT + 1280000;
    const size_t o_H     = o_SQ + 40192;
    const size_t o_NBR   = o_H + 1280000;
    const size_t o_HOUT  = o_NBR + 1280000;

    float* stats = (float*)(ws + o_stats);
    float* X     = (float*)(ws + o_X);
    float* XT    = (float*)(ws + o_XT);
    float* SQ    = (float*)(ws + o_SQ);
    float* H     = (float*)(ws + o_H);
    int*   NBR   = (int*)  (ws + o_NBR);
    float* HOUT  = (float*)(ws + o_HOUT);
    float* out   = (float*)d_out;

    (void)hipMemsetAsync(stats, 0, 2 * sizeof(float), stream);
    stats_kernel<<<512, 256, 0, stream>>>(pop, stats);
    feat_kernel<<<N_NODES, 256, 0, stream>>>(pop, conv_w, conv_b, gamma, beta, stats, X, XT, SQ);

    const int nqb = (N_NODES + QB - 1) / QB;                 // 3334
    const size_t keys_bytes = (size_t)QB * NPAD * 4;         // 120192 B dynamic LDS
    knn3_kernel<<<nqb, BT, keys_bytes, stream>>>(X, XT, SQ, NBR);

    for (int l = 0; l < 3; ++l) {
        gcn_mm<<<N_NODES / 8, 256, 0, stream>>>(X, gcn_ws + l * D_DIM * D_DIM, H);
        gcn_agg<<<N_NODES / 8, 256, 0, stream>>>(H, NBR, gcn_bs + l * D_DIM, X, 1);
    }
    out_mm<<<(N_NODES + 255) / 256, 256, 0, stream>>>(X, out_w, HOUT);
    final_kernel<<<(N_NODES + 255) / 256, 256, 0, stream>>>(HOUT, NBR, out_b, out);
}